// Round 1
// baseline (127.914 us; speedup 1.0000x reference)
//
#include <hip/hip_runtime.h>

#define B_SZ   32
#define T_LEN  160000
#define NFFT   1024
#define HOP    320
#define FRAMES 501
#define NBINS  513
#define PADL   512

#define MROWS_BF  1024                    // interleaved cos/sin rows staged as bf16 (bins 0..511)
#define XP_STRIDE 164864                  // padded per-batch xp length (elements)
#define WS_XP_OFF (MROWS_BF * NFFT)       // ushort-element offset of xp region in ws
#define XP_G8_PB  (XP_STRIDE / 8)         // 20608 8-elem groups per batch

// prep-kernel block ranges
#define PB_BASIS  512                     // basis convert (131072 thr x 8 elems)
#define PB_XP     2576                    // xp convert    (659456 thr x 8 elems)
#define PB_BIN512 4012                    // bin512        (16048 waves >= 16032 dots)
#define PREP_BLOCKS (PB_BASIS + PB_XP + PB_BIN512)

#define NT 16                             // K-tiles of 64 over NFFT=1024

typedef __bf16 bf16x8  __attribute__((ext_vector_type(8)));
typedef float  floatx4 __attribute__((ext_vector_type(4)));

__device__ __forceinline__ unsigned short f2bf(float f) {
    unsigned u = __builtin_bit_cast(unsigned, f);
    u += 0x7FFFu + ((u >> 16) & 1u);      // round-to-nearest-even
    return (unsigned short)(u >> 16);
}

__device__ __forceinline__ void gl_lds16(const void* g, void* l) {
    __builtin_amdgcn_global_load_lds(
        (const __attribute__((address_space(1))) unsigned int*)g,
        (__attribute__((address_space(3))) unsigned int*)l, 16, 0, 0);
}

// ---- fused prep (verified R5): basis->bf16 | x->padded bf16 xp | bin512 fp32 ----
__global__ void stft_prep(const float* __restrict__ x,
                          const float* __restrict__ basis,
                          unsigned short* __restrict__ basisb,
                          unsigned short* __restrict__ xpb,
                          float* __restrict__ out) {
    const int blk = blockIdx.x;
    const int tid = threadIdx.x;

    if (blk < PB_BASIS) {
        const int gid = blk * 256 + tid;          // 8 elems per thread, exact cover
        const int row = gid >> 7;                 // 0..1023
        const int col = (gid & 127) * 8;
        const int j = row >> 1, c = row & 1;
        const float* src = basis + (size_t)(j + c * NBINS) * NFFT + col;
        const float4 v0 = *(const float4*)(src);
        const float4 v1 = *(const float4*)(src + 4);
        ushort4 o0, o1;
        o0.x = f2bf(v0.x); o0.y = f2bf(v0.y); o0.z = f2bf(v0.z); o0.w = f2bf(v0.w);
        o1.x = f2bf(v1.x); o1.y = f2bf(v1.y); o1.z = f2bf(v1.z); o1.w = f2bf(v1.w);
        unsigned short* d = basisb + ((size_t)row << 10) + col;
        *(ushort4*)(d)     = o0;
        *(ushort4*)(d + 4) = o1;
    } else if (blk < PB_BASIS + PB_XP) {
        const int i   = (blk - PB_BASIS) * 256 + tid;   // 0..659455, exact cover
        const int b   = i / XP_G8_PB;
        const int pos = (i - b * XP_G8_PB) * 8;         // boundaries (512,160512) are %8==0
        ushort4 o0 = {0,0,0,0}, o1 = {0,0,0,0};
        if (pos >= PADL && pos < T_LEN + PADL) {
            const float* src = x + (size_t)b * T_LEN + (pos - PADL);
            const float4 v0 = *(const float4*)(src);
            const float4 v1 = *(const float4*)(src + 4);
            o0.x = f2bf(v0.x); o0.y = f2bf(v0.y); o0.z = f2bf(v0.z); o0.w = f2bf(v0.w);
            o1.x = f2bf(v1.x); o1.y = f2bf(v1.y); o1.z = f2bf(v1.z); o1.w = f2bf(v1.w);
        }
        unsigned short* d = xpb + (size_t)b * XP_STRIDE + pos;
        *(ushort4*)(d)     = o0;
        *(ushort4*)(d + 4) = o1;
    } else {
        const int lane = tid & 63;
        const int d    = (blk - PB_BASIS - PB_XP) * 4 + (tid >> 6);  // wave-dot id
        if (d >= B_SZ * FRAMES) return;                              // wave-uniform
        const int b = d / FRAMES;
        const int f = d - b * FRAMES;
        const float* br = basis + (size_t)512 * NFFT + lane * 16;
        const float* xb = x + (size_t)b * T_LEN;
        const int base = f * HOP - PADL + lane * 16;
        float sum = 0.f;
        #pragma unroll
        for (int c = 0; c < 4; ++c) {
            const int xi = base + c * 4;
            const float4 bv = *(const float4*)(br + c * 4);
            float4 v;
            if (xi >= 0 && xi + 3 < T_LEN) {
                v = *(const float4*)(xb + xi);
            } else {
                v.x = (xi + 0 >= 0 && xi + 0 < T_LEN) ? xb[xi + 0] : 0.f;
                v.y = (xi + 1 >= 0 && xi + 1 < T_LEN) ? xb[xi + 1] : 0.f;
                v.z = (xi + 2 >= 0 && xi + 2 < T_LEN) ? xb[xi + 2] : 0.f;
                v.w = (xi + 3 >= 0 && xi + 3 < T_LEN) ? xb[xi + 3] : 0.f;
            }
            sum += bv.x * v.x + bv.y * v.y + bv.z * v.z + bv.w * v.w;
        }
        #pragma unroll
        for (int off = 32; off >= 1; off >>= 1) sum += __shfl_down(sum, off);
        if (lane == 0) {
            float2 val; val.x = sum; val.y = 0.f;
            *(float2*)(out + (((size_t)b * NBINS + 512) * FRAMES + f) * 2) = val;
        }
    }
}

// ---- MFMA GEMM v2: 256x256 tile, 8 waves (2M x 4N), BK=64.
// 4-phase-per-K-tile pipelined schedule: counted vmcnt(8) (never drained to 0
// in the loop), raw s_barrier, setprio(1) around MFMA clusters, XOR-swizzled
// LDS (conflict-free ds_read_b128; swizzle applied on the pre-swizzled GLOBAL
// source so the global_load_lds destination stays linear).
//
// LDS: lds[buf][part][row*32+col], part: 0=A-kh0 1=A-kh1 2=B-kh0 3=B-kh1.
// Half-tile = one part = 256 rows x 32 k x 2B = 16 KB (2 gl_lds16/thread).
// Stage ledger (per K-tile t, phases p1..p4 = (kh,nh) in (0,0),(0,1),(1,0),(1,1)):
//   p1: issue A-kh1(t+1)   p2: issue B-kh1(t+1), vmcnt(8)
//   p3: issue A-kh0(t+2)   p4: issue B-kh0(t+2), vmcnt(8)
// vmcnt(8) = newest 4 half-tiles may be in flight; guarantees (A0,B0) of the
// next tile before its p1 and (A1,B1) before its p3. All overwrites land >=1
// barrier after the region's last lgkmcnt(0)-drained read. Tail stays uniform
// via wrap-around staging (valid addresses, never read).
__launch_bounds__(512, 2)
__global__ void stft_mfma_kernel(const unsigned short* __restrict__ basisb,
                                 const unsigned short* __restrict__ xpb,
                                 float* __restrict__ out) {
    __shared__ unsigned short lds[2][4][8192];   // 128 KiB, 1 block/CU

    const int tid  = threadIdx.x;
    const int lane = tid & 63;
    const int w    = tid >> 6;        // wave 0..7
    const int wm   = w & 1;           // m-half of 256 (128 rows)
    const int wn   = w >> 1;          // n-quarter of 256 (64 frames)
    const int r0   = lane & 15;
    const int quad = lane >> 4;
    // swizzled column (elems) within a 64-B row: slot = quad ^ ((row>>1)&3)
    const int ce   = (quad ^ ((r0 >> 1) & 3)) * 8;

    const int fg0 = blockIdx.x * 256;           // frame tile base (0,256)
    const int mg0 = blockIdx.y * 256;           // row tile base (0..768)
    const int b   = blockIdx.z;
    const unsigned short* xpbb = xpb + (size_t)b * XP_STRIDE;

    // staging precompute: 2 issues/thread per half-tile; LDS dest linear,
    // global source column pre-swizzled with the same involution as the reads
    const int i0 = tid, i1 = 512 + tid;
    const int row0 = i0 >> 2, row1 = i1 >> 2;
    const int c0 = ((((i0 & 3) << 4) ^ (((row0 >> 1) & 3) << 4)) >> 1);
    const int c1 = ((((i1 & 3) << 4) ^ (((row1 >> 1) & 3) << 4)) >> 1);
    const unsigned short* arow0 = basisb + ((size_t)(mg0 + row0) << 10) + c0;
    const unsigned short* arow1 = basisb + ((size_t)(mg0 + row1) << 10) + c1;
    const unsigned short* brow0 = xpbb + (size_t)(fg0 + row0) * HOP + c0;
    const unsigned short* brow1 = xpbb + (size_t)(fg0 + row1) * HOP + c1;

#define STAGE_A(kt, kh, buf) do {                                   \
    const int ko_ = ((kt) & (NT - 1)) * 64 + (kh) * 32;             \
    gl_lds16(arow0 + ko_, &lds[buf][kh][i0 * 8]);                   \
    gl_lds16(arow1 + ko_, &lds[buf][kh][i1 * 8]);                   \
} while (0)
#define STAGE_B(kt, kh, buf) do {                                   \
    const int ko_ = ((kt) & (NT - 1)) * 64 + (kh) * 32;             \
    gl_lds16(brow0 + ko_, &lds[buf][2 + (kh)][i0 * 8]);             \
    gl_lds16(brow1 + ko_, &lds[buf][2 + (kh)][i1 * 8]);             \
} while (0)

    floatx4 acc[8][4] = {};
    bf16x8 af[8], bf[2];

#define LOAD_A(kh, buf) do {                                                  \
    const unsigned short* pa_ = &lds[buf][kh][(wm * 128 + r0) * 32 + ce];     \
    _Pragma("unroll")                                                         \
    for (int mt = 0; mt < 8; ++mt) af[mt] = *(const bf16x8*)(pa_ + mt * 512); \
} while (0)
#define LOAD_B(kh, nh, buf) do {                                              \
    const unsigned short* pb_ =                                               \
        &lds[buf][2 + (kh)][(wn * 64 + (nh) * 32 + r0) * 32 + ce];            \
    bf[0] = *(const bf16x8*)(pb_);                                            \
    bf[1] = *(const bf16x8*)(pb_ + 512);                                      \
} while (0)
#define MFMA16(nh) do {                                                       \
    _Pragma("unroll")                                                         \
    for (int mt = 0; mt < 8; ++mt) {                                          \
        acc[mt][(nh) * 2]     = __builtin_amdgcn_mfma_f32_16x16x32_bf16(      \
            af[mt], bf[0], acc[mt][(nh) * 2], 0, 0, 0);                       \
        acc[mt][(nh) * 2 + 1] = __builtin_amdgcn_mfma_f32_16x16x32_bf16(      \
            af[mt], bf[1], acc[mt][(nh) * 2 + 1], 0, 0, 0);                   \
    }                                                                         \
} while (0)
#define VMC8 asm volatile("s_waitcnt vmcnt(8)" ::: "memory")
#define PHASE(kh, nh, buf, DO_STAGE, DO_VM) do {                              \
    if ((nh) == 0) { LOAD_A(kh, buf); }                                       \
    LOAD_B(kh, nh, buf);                                                      \
    DO_STAGE;                                                                 \
    __builtin_amdgcn_s_barrier();                                             \
    asm volatile("s_waitcnt lgkmcnt(0)" ::: "memory");                        \
    __builtin_amdgcn_s_setprio(1);                                            \
    MFMA16(nh);                                                               \
    __builtin_amdgcn_s_setprio(0);                                            \
    DO_VM;                                                                    \
    __builtin_amdgcn_s_barrier();                                             \
} while (0)

    // prologue: A0(0) B0(0) A1(0) B1(0) A0(1) B0(1); vmcnt(8) => A0(0),B0(0) landed
    STAGE_A(0, 0, 0); STAGE_B(0, 0, 0);
    STAGE_A(0, 1, 0); STAGE_B(0, 1, 0);
    STAGE_A(1, 0, 1); STAGE_B(1, 0, 1);
    VMC8;
    __builtin_amdgcn_s_barrier();

    #pragma unroll 1
    for (int t = 0; t < NT; t += 2) {
        // K-tile t  (buf0)
        PHASE(0, 0, 0, STAGE_A(t + 1, 1, 1), );
        PHASE(0, 1, 0, STAGE_B(t + 1, 1, 1), VMC8);
        PHASE(1, 0, 0, STAGE_A(t + 2, 0, 0), );
        PHASE(1, 1, 0, STAGE_B(t + 2, 0, 0), VMC8);
        // K-tile t+1 (buf1)
        PHASE(0, 0, 1, STAGE_A(t + 2, 1, 0), );
        PHASE(0, 1, 1, STAGE_B(t + 2, 1, 0), VMC8);
        PHASE(1, 0, 1, STAGE_A(t + 3, 0, 1), );
        PHASE(1, 1, 1, STAGE_B(t + 3, 0, 1), VMC8);
    }

    // epilogue: rows are interleaved (cos,sin) pairs -> coalesced float2 stores
    const int mb = mg0 + wm * 128 + quad * 4;     // even
    const int fb = fg0 + wn * 64 + r0;
    #pragma unroll
    for (int nt = 0; nt < 4; ++nt) {
        const int f = fb + nt * 16;
        if (f >= FRAMES) continue;
        #pragma unroll
        for (int mt = 0; mt < 8; ++mt) {
            const int mrow = mb + mt * 16;
            const floatx4 v = acc[mt][nt];
            #pragma unroll
            for (int p = 0; p < 2; ++p) {
                const int bin = (mrow + 2 * p) >> 1;
                float2 val;
                val.x = v[2 * p];      // cos
                val.y = v[2 * p + 1];  // sin
                *(float2*)(out + (((size_t)b * NBINS + bin) * FRAMES + f) * 2) = val;
            }
        }
    }
    // drain wrap-around garbage LDS-DMA before the workgroup's LDS is freed
    asm volatile("s_waitcnt vmcnt(0)" ::: "memory");

#undef STAGE_A
#undef STAGE_B
#undef LOAD_A
#undef LOAD_B
#undef MFMA16
#undef VMC8
#undef PHASE
}

extern "C" void kernel_launch(void* const* d_in, const int* in_sizes, int n_in,
                              void* d_out, int out_size, void* d_ws, size_t ws_size,
                              hipStream_t stream) {
    const float* x     = (const float*)d_in[0];
    const float* basis = (const float*)d_in[1];
    float* out         = (float*)d_out;

    unsigned short* basis_bf = (unsigned short*)d_ws;
    unsigned short* xp_bf    = (unsigned short*)d_ws + WS_XP_OFF;

    stft_prep<<<dim3(PREP_BLOCKS), dim3(256), 0, stream>>>(x, basis, basis_bf, xp_bf, out);

    dim3 grid(2, 4, B_SZ);   // 2 frame-tiles x 4 row-tiles x 32 batches = 256 blocks (1/CU)
    stft_mfma_kernel<<<grid, dim3(512), 0, stream>>>(basis_bf, xp_bf, out);
}

// Round 2
// 126.284 us; speedup vs baseline: 1.0129x; 1.0129x over previous
//
#include <hip/hip_runtime.h>

#define B_SZ   32
#define T_LEN  160000
#define NFFT   1024
#define HOP    320
#define FRAMES 501
#define NBINS  513
#define PADL   512

#define MROWS_BF  1024                    // interleaved cos/sin rows staged as bf16 (bins 0..511)
#define XP_STRIDE 164864                  // padded per-batch xp length (elements)
#define WS_XP_OFF (MROWS_BF * NFFT)       // ushort-element offset of xp region in ws
#define XP_G8_PB  (XP_STRIDE / 8)         // 20608 8-elem groups per batch

// prep-kernel block ranges
#define PB_BASIS  512                     // basis convert (131072 thr x 8 elems)
#define PB_XP     2576                    // xp convert    (659456 thr x 8 elems)
#define PB_BIN512 4012                    // bin512        (16048 waves >= 16032 dots)
#define PREP_BLOCKS (PB_BASIS + PB_XP + PB_BIN512)

#define NT 16                             // K-tiles of 64 over NFFT=1024

typedef __bf16 bf16x8  __attribute__((ext_vector_type(8)));
typedef float  floatx4 __attribute__((ext_vector_type(4)));

__device__ __forceinline__ unsigned short f2bf(float f) {
    unsigned u = __builtin_bit_cast(unsigned, f);
    u += 0x7FFFu + ((u >> 16) & 1u);      // round-to-nearest-even
    return (unsigned short)(u >> 16);
}

__device__ __forceinline__ void gl_lds16(const void* g, void* l) {
    __builtin_amdgcn_global_load_lds(
        (const __attribute__((address_space(1))) unsigned int*)g,
        (__attribute__((address_space(3))) unsigned int*)l, 16, 0, 0);
}

// ---- fused prep (verified R5): basis->bf16 | x->padded bf16 xp | bin512 fp32 ----
__global__ void stft_prep(const float* __restrict__ x,
                          const float* __restrict__ basis,
                          unsigned short* __restrict__ basisb,
                          unsigned short* __restrict__ xpb,
                          float* __restrict__ out) {
    const int blk = blockIdx.x;
    const int tid = threadIdx.x;

    if (blk < PB_BASIS) {
        const int gid = blk * 256 + tid;          // 8 elems per thread, exact cover
        const int row = gid >> 7;                 // 0..1023
        const int col = (gid & 127) * 8;
        const int j = row >> 1, c = row & 1;
        const float* src = basis + (size_t)(j + c * NBINS) * NFFT + col;
        const float4 v0 = *(const float4*)(src);
        const float4 v1 = *(const float4*)(src + 4);
        ushort4 o0, o1;
        o0.x = f2bf(v0.x); o0.y = f2bf(v0.y); o0.z = f2bf(v0.z); o0.w = f2bf(v0.w);
        o1.x = f2bf(v1.x); o1.y = f2bf(v1.y); o1.z = f2bf(v1.z); o1.w = f2bf(v1.w);
        unsigned short* d = basisb + ((size_t)row << 10) + col;
        *(ushort4*)(d)     = o0;
        *(ushort4*)(d + 4) = o1;
    } else if (blk < PB_BASIS + PB_XP) {
        const int i   = (blk - PB_BASIS) * 256 + tid;   // 0..659455, exact cover
        const int b   = i / XP_G8_PB;
        const int pos = (i - b * XP_G8_PB) * 8;         // boundaries (512,160512) are %8==0
        ushort4 o0 = {0,0,0,0}, o1 = {0,0,0,0};
        if (pos >= PADL && pos < T_LEN + PADL) {
            const float* src = x + (size_t)b * T_LEN + (pos - PADL);
            const float4 v0 = *(const float4*)(src);
            const float4 v1 = *(const float4*)(src + 4);
            o0.x = f2bf(v0.x); o0.y = f2bf(v0.y); o0.z = f2bf(v0.z); o0.w = f2bf(v0.w);
            o1.x = f2bf(v1.x); o1.y = f2bf(v1.y); o1.z = f2bf(v1.z); o1.w = f2bf(v1.w);
        }
        unsigned short* d = xpb + (size_t)b * XP_STRIDE + pos;
        *(ushort4*)(d)     = o0;
        *(ushort4*)(d + 4) = o1;
    } else {
        const int lane = tid & 63;
        const int d    = (blk - PB_BASIS - PB_XP) * 4 + (tid >> 6);  // wave-dot id
        if (d >= B_SZ * FRAMES) return;                              // wave-uniform
        const int b = d / FRAMES;
        const int f = d - b * FRAMES;
        const float* br = basis + (size_t)512 * NFFT + lane * 16;
        const float* xb = x + (size_t)b * T_LEN;
        const int base = f * HOP - PADL + lane * 16;
        float sum = 0.f;
        #pragma unroll
        for (int c = 0; c < 4; ++c) {
            const int xi = base + c * 4;
            const float4 bv = *(const float4*)(br + c * 4);
            float4 v;
            if (xi >= 0 && xi + 3 < T_LEN) {
                v = *(const float4*)(xb + xi);
            } else {
                v.x = (xi + 0 >= 0 && xi + 0 < T_LEN) ? xb[xi + 0] : 0.f;
                v.y = (xi + 1 >= 0 && xi + 1 < T_LEN) ? xb[xi + 1] : 0.f;
                v.z = (xi + 2 >= 0 && xi + 2 < T_LEN) ? xb[xi + 2] : 0.f;
                v.w = (xi + 3 >= 0 && xi + 3 < T_LEN) ? xb[xi + 3] : 0.f;
            }
            sum += bv.x * v.x + bv.y * v.y + bv.z * v.z + bv.w * v.w;
        }
        #pragma unroll
        for (int off = 32; off >= 1; off >>= 1) sum += __shfl_down(sum, off);
        if (lane == 0) {
            float2 val; val.x = sum; val.y = 0.f;
            *(float2*)(out + (((size_t)b * NBINS + 512) * FRAMES + f) * 2) = val;
        }
    }
}

// ---- MFMA GEMM v3: 256x256 tile, 8 waves (2M x 4N), BK=64.
// Same verified 4-phase-per-K-tile schedule as v2 (counted vmcnt(8), raw
// s_barrier, setprio around MFMA, XOR-swizzled conflict-free LDS).
// v3 change: block->XCD remap. grid(B_SZ, 2, 4) makes linear block id
// b + 32*(x+2y), so XCD = b%8: each XCD owns 4 batches x all 8 tiles =
// 32 co-resident blocks. Per-XCD footprint = A 2MB + 4 x xp 330KB = 3.3MB
// < 4MB L2, so A re-reads (8x) and B frame-overlap re-reads (3.1x) become
// L2 hits -> staging latency back to ~200cyc, inside the vmcnt(8) cover.
__launch_bounds__(512, 2)
__global__ void stft_mfma_kernel(const unsigned short* __restrict__ basisb,
                                 const unsigned short* __restrict__ xpb,
                                 float* __restrict__ out) {
    __shared__ unsigned short lds[2][4][8192];   // 128 KiB, 1 block/CU

    const int tid  = threadIdx.x;
    const int lane = tid & 63;
    const int w    = tid >> 6;        // wave 0..7
    const int wm   = w & 1;           // m-half of 256 (128 rows)
    const int wn   = w >> 1;          // n-quarter of 256 (64 frames)
    const int r0   = lane & 15;
    const int quad = lane >> 4;
    // swizzled column (elems) within a 64-B row: slot = quad ^ ((row>>1)&3)
    const int ce   = (quad ^ ((r0 >> 1) & 3)) * 8;

    const int b   = blockIdx.x;                 // batch fastest -> XCD = b%8
    const int fg0 = blockIdx.y * 256;           // frame tile base (0,256)
    const int mg0 = blockIdx.z * 256;           // row tile base (0..768)
    const unsigned short* xpbb = xpb + (size_t)b * XP_STRIDE;

    // staging precompute: 2 issues/thread per half-tile; LDS dest linear,
    // global source column pre-swizzled with the same involution as the reads
    const int i0 = tid, i1 = 512 + tid;
    const int row0 = i0 >> 2, row1 = i1 >> 2;
    const int c0 = ((((i0 & 3) << 4) ^ (((row0 >> 1) & 3) << 4)) >> 1);
    const int c1 = ((((i1 & 3) << 4) ^ (((row1 >> 1) & 3) << 4)) >> 1);
    const unsigned short* arow0 = basisb + ((size_t)(mg0 + row0) << 10) + c0;
    const unsigned short* arow1 = basisb + ((size_t)(mg0 + row1) << 10) + c1;
    const unsigned short* brow0 = xpbb + (size_t)(fg0 + row0) * HOP + c0;
    const unsigned short* brow1 = xpbb + (size_t)(fg0 + row1) * HOP + c1;

#define STAGE_A(kt, kh, buf) do {                                   \
    const int ko_ = ((kt) & (NT - 1)) * 64 + (kh) * 32;             \
    gl_lds16(arow0 + ko_, &lds[buf][kh][i0 * 8]);                   \
    gl_lds16(arow1 + ko_, &lds[buf][kh][i1 * 8]);                   \
} while (0)
#define STAGE_B(kt, kh, buf) do {                                   \
    const int ko_ = ((kt) & (NT - 1)) * 64 + (kh) * 32;             \
    gl_lds16(brow0 + ko_, &lds[buf][2 + (kh)][i0 * 8]);             \
    gl_lds16(brow1 + ko_, &lds[buf][2 + (kh)][i1 * 8]);             \
} while (0)

    floatx4 acc[8][4] = {};
    bf16x8 af[8], bf[2];

#define LOAD_A(kh, buf) do {                                                  \
    const unsigned short* pa_ = &lds[buf][kh][(wm * 128 + r0) * 32 + ce];     \
    _Pragma("unroll")                                                         \
    for (int mt = 0; mt < 8; ++mt) af[mt] = *(const bf16x8*)(pa_ + mt * 512); \
} while (0)
#define LOAD_B(kh, nh, buf) do {                                              \
    const unsigned short* pb_ =                                               \
        &lds[buf][2 + (kh)][(wn * 64 + (nh) * 32 + r0) * 32 + ce];            \
    bf[0] = *(const bf16x8*)(pb_);                                            \
    bf[1] = *(const bf16x8*)(pb_ + 512);                                      \
} while (0)
#define MFMA16(nh) do {                                                       \
    _Pragma("unroll")                                                         \
    for (int mt = 0; mt < 8; ++mt) {                                          \
        acc[mt][(nh) * 2]     = __builtin_amdgcn_mfma_f32_16x16x32_bf16(      \
            af[mt], bf[0], acc[mt][(nh) * 2], 0, 0, 0);                       \
        acc[mt][(nh) * 2 + 1] = __builtin_amdgcn_mfma_f32_16x16x32_bf16(      \
            af[mt], bf[1], acc[mt][(nh) * 2 + 1], 0, 0, 0);                   \
    }                                                                         \
} while (0)
#define VMC8 asm volatile("s_waitcnt vmcnt(8)" ::: "memory")
#define PHASE(kh, nh, buf, DO_STAGE, DO_VM) do {                              \
    if ((nh) == 0) { LOAD_A(kh, buf); }                                       \
    LOAD_B(kh, nh, buf);                                                      \
    DO_STAGE;                                                                 \
    __builtin_amdgcn_s_barrier();                                             \
    asm volatile("s_waitcnt lgkmcnt(0)" ::: "memory");                        \
    __builtin_amdgcn_s_setprio(1);                                            \
    MFMA16(nh);                                                               \
    __builtin_amdgcn_s_setprio(0);                                            \
    DO_VM;                                                                    \
    __builtin_amdgcn_s_barrier();                                             \
} while (0)

    // prologue: A0(0) B0(0) A1(0) B1(0) A0(1) B0(1); vmcnt(8) => A0(0),B0(0) landed
    STAGE_A(0, 0, 0); STAGE_B(0, 0, 0);
    STAGE_A(0, 1, 0); STAGE_B(0, 1, 0);
    STAGE_A(1, 0, 1); STAGE_B(1, 0, 1);
    VMC8;
    __builtin_amdgcn_s_barrier();

    #pragma unroll 1
    for (int t = 0; t < NT; t += 2) {
        // K-tile t  (buf0)
        PHASE(0, 0, 0, STAGE_A(t + 1, 1, 1), );
        PHASE(0, 1, 0, STAGE_B(t + 1, 1, 1), VMC8);
        PHASE(1, 0, 0, STAGE_A(t + 2, 0, 0), );
        PHASE(1, 1, 0, STAGE_B(t + 2, 0, 0), VMC8);
        // K-tile t+1 (buf1)
        PHASE(0, 0, 1, STAGE_A(t + 2, 1, 0), );
        PHASE(0, 1, 1, STAGE_B(t + 2, 1, 0), VMC8);
        PHASE(1, 0, 1, STAGE_A(t + 3, 0, 1), );
        PHASE(1, 1, 1, STAGE_B(t + 3, 0, 1), VMC8);
    }

    // epilogue: rows are interleaved (cos,sin) pairs -> coalesced float2 stores
    const int mb = mg0 + wm * 128 + quad * 4;     // even
    const int fb = fg0 + wn * 64 + r0;
    #pragma unroll
    for (int nt = 0; nt < 4; ++nt) {
        const int f = fb + nt * 16;
        if (f >= FRAMES) continue;
        #pragma unroll
        for (int mt = 0; mt < 8; ++mt) {
            const int mrow = mb + mt * 16;
            const floatx4 v = acc[mt][nt];
            #pragma unroll
            for (int p = 0; p < 2; ++p) {
                const int bin = (mrow + 2 * p) >> 1;
                float2 val;
                val.x = v[2 * p];      // cos
                val.y = v[2 * p + 1];  // sin
                *(float2*)(out + (((size_t)b * NBINS + bin) * FRAMES + f) * 2) = val;
            }
        }
    }
    // drain wrap-around garbage LDS-DMA before the workgroup's LDS is freed
    asm volatile("s_waitcnt vmcnt(0)" ::: "memory");

#undef STAGE_A
#undef STAGE_B
#undef LOAD_A
#undef LOAD_B
#undef MFMA16
#undef VMC8
#undef PHASE
}

extern "C" void kernel_launch(void* const* d_in, const int* in_sizes, int n_in,
                              void* d_out, int out_size, void* d_ws, size_t ws_size,
                              hipStream_t stream) {
    const float* x     = (const float*)d_in[0];
    const float* basis = (const float*)d_in[1];
    float* out         = (float*)d_out;

    unsigned short* basis_bf = (unsigned short*)d_ws;
    unsigned short* xp_bf    = (unsigned short*)d_ws + WS_XP_OFF;

    stft_prep<<<dim3(PREP_BLOCKS), dim3(256), 0, stream>>>(x, basis, basis_bf, xp_bf, out);

    // batch fastest -> XCD = b%8: 4 batches x all 8 tiles per XCD (3.3MB < L2)
    dim3 grid(B_SZ, 2, 4);   // 256 blocks, 1/CU, all co-resident
    stft_mfma_kernel<<<grid, dim3(512), 0, stream>>>(basis_bf, xp_bf, out);
}